// Round 7
// baseline (503.439 us; speedup 1.0000x reference)
//
#include <hip/hip_runtime.h>
#include <hip/hip_bf16.h>

// Fused: segment_sum(x_l[edge_lit] by sorted edge_clause) -> [msg|h0] @ [W_ih|W_hh]^T + b
//        -> LSTM cell epilogue -> h_new, c_new.
// Device float dtype (fp32 vs bf16) detected at runtime (flag in d_ws); both template
// variants launch, wrong one exits immediately.
// build_rowptr: CSR offsets for all clauses -> d_ws.
// prepack: W -> bf16 Bpack[kk][n][lq]*16B + fp32 bias sum in d_ws.
// Main: one block = 64 clause rows, 512 threads = 8 waves. LDS = 64 KB.
//   Phase A: rowptr slice -> lane regs; h0 tile cvt+staged (coalesced).
//   Phase B: segment-sum, ONE QUARTER-WAVE PER 2 CLAUSES: contiguous edge range,
//            16 lit-indices preloaded in one parallel round, 1-deep pipelined gather,
//            no cross-lane reduce. -> swizzled msg tile.
//   [barrier]
//   Phase C: c0 prefetch to regs (T14), then GEMM (A from LDS, B from prepacked global).
//   Phase D: LSTM gate math in regs.
//   Phase E: h AND c staged through 64K LDS in ONE pass -> full-line coalesced stores.
// Wave w owns output dims d in [w*16, w*16+16) for ALL 4 gates (epilogue wave-local).
// Occupancy: ~64 arch VGPR + 64 acc AGPR -> 128-reg bin -> 4 waves/SIMD cap (structural);
// we optimize serial chains + ILP, not waves.

using frag_ab = __attribute__((ext_vector_type(8))) short;  // 8 bf16 (4 VGPRs)
using frag_cd = __attribute__((ext_vector_type(4))) float;  // 4 fp32

__device__ __forceinline__ float bf2f(unsigned short u) {
    union { unsigned u; float f; } v; v.u = ((unsigned)u) << 16; return v.f;
}
__device__ __forceinline__ unsigned short f2bf(float f) {
    __hip_bfloat16 h = __float2bfloat16(f);   // RNE, native cvt on gfx950
    return *reinterpret_cast<unsigned short*>(&h);
}
__device__ __forceinline__ float sigm(float x) {
    return 1.0f / (1.0f + __expf(-x));
}
__device__ __forceinline__ float tanh_fast(float x) {
    x = fminf(fmaxf(x, -20.0f), 20.0f);
    float t = __expf(2.0f * x);
    return (t - 1.0f) / (t + 1.0f);
}
__device__ __forceinline__ frag_ab load8_fp32(const float* p) {
    float4 a = *reinterpret_cast<const float4*>(p);
    float4 b = *reinterpret_cast<const float4*>(p + 4);
    frag_ab r;
    r[0] = (short)f2bf(a.x); r[1] = (short)f2bf(a.y);
    r[2] = (short)f2bf(a.z); r[3] = (short)f2bf(a.w);
    r[4] = (short)f2bf(b.x); r[5] = (short)f2bf(b.y);
    r[6] = (short)f2bf(b.z); r[7] = (short)f2bf(b.w);
    return r;
}

// ws layout
#define WS_BPACK_OFF  0           // 16384 * 16B = 256 KB
#define WS_BIAS_OFF   262144     // 512 * 4B
#define WS_FLAG_OFF   264192     // 4B
#define WS_ROWPTR_OFF 264704     // (n_clause+1) * 4B  (~1.6 MB)

// Decide device float dtype: sample even-indexed 16-bit words of x_l.
// fp32 -> low mantissa halves (uniform) -> ~25% have exp field >= 0xC0.
// bf16 -> values of N(0,1) -> exp field < 0x90 always.
__global__ void detect_fmt(const unsigned short* __restrict__ x, int* __restrict__ flag) {
    int t = threadIdx.x;
    int cnt = 0;
    for (int i = t; i < 4096; i += 64) {
        unsigned e = (x[2 * i] >> 7) & 0xFF;
        cnt += (e >= 0xC0) ? 1 : 0;
    }
    #pragma unroll
    for (int s = 32; s; s >>= 1) cnt += __shfl_xor(cnt, s);
    if (t == 0) *flag = (cnt > 64) ? 1 : 0;   // 1 = fp32, 0 = bf16
}

// CSR row offsets for every clause (dtype-independent).
__global__ void build_rowptr(const int* __restrict__ edge_clause, int* __restrict__ rowptr,
                             int n_edges, int n_clause) {
    int idx = blockIdx.x * blockDim.x + threadIdx.x;
    if (idx > n_clause) return;
    int lo = 0, hi = n_edges;
    while (lo < hi) {
        int mid = (lo + hi) >> 1;
        if (edge_clause[mid] < idx) lo = mid + 1; else hi = mid;
    }
    rowptr[idx] = lo;
}

// Pack W_ih/W_hh into bf16 Bpack: chunk idx = (kk*512 + n)*4 + lq holds 8 bf16 of
// k = (kk&3)*32 + lq*8 .. +8 from row n of (kk<4 ? W_ih : W_hh). Also bias sum fp32.
template <int FP32IN>
__global__ void prepack(const void* __restrict__ W_ih_, const void* __restrict__ W_hh_,
                        const void* __restrict__ b_ih_, const void* __restrict__ b_hh_,
                        unsigned short* __restrict__ Bpack, float* __restrict__ bias,
                        const int* __restrict__ flag) {
    if (*flag != FP32IN) return;
    int idx = blockIdx.x * blockDim.x + threadIdx.x;
    if (idx < 16384) {
        int kk = idx >> 11;
        int n  = (idx >> 2) & 511;
        int lq = idx & 3;
        int ksrc = (kk & 3) * 32 + lq * 8;
        frag_ab v;
        if constexpr (FP32IN) {
            const float* W = (kk < 4) ? (const float*)W_ih_ : (const float*)W_hh_;
            v = load8_fp32(W + (size_t)n * 128 + ksrc);
        } else {
            const unsigned short* W =
                (kk < 4) ? (const unsigned short*)W_ih_ : (const unsigned short*)W_hh_;
            v = *reinterpret_cast<const frag_ab*>(W + (size_t)n * 128 + ksrc);
        }
        *reinterpret_cast<frag_ab*>(Bpack + (size_t)idx * 8) = v;
    }
    if (idx < 512) {
        float b;
        if constexpr (FP32IN)
            b = ((const float*)b_ih_)[idx] + ((const float*)b_hh_)[idx];
        else
            b = bf2f(((const unsigned short*)b_ih_)[idx]) +
                bf2f(((const unsigned short*)b_hh_)[idx]);
        bias[idx] = b;
    }
}

template <int FP32IN>
__global__ __launch_bounds__(512, 4) void lit2clause_fused(
    const void* __restrict__ x_l_,
    const void* __restrict__ h0_,
    const void* __restrict__ c0_,
    const unsigned short* __restrict__ Bpack,
    const float* __restrict__ bias,
    const int*  __restrict__ rowptr_g,
    const int*  __restrict__ edge_lit,
    void* __restrict__ out_,
    const int* __restrict__ fmt_flag,
    int n_edges, int n_clause)
{
    if (*fmt_flag != FP32IN) return;   // wrong-dtype variant: bail (uniform, pre-barrier)

    // SH: [msg 16K | h0 16K] bf16 [64][128], 256B/row, XOR swizzle byte^=(row&7)<<4.
    // Reused post-GEMM as fp32 [128][128] (h rows 0-63, c rows 64-127) out-staging.
    __shared__ __align__(16) unsigned char SH[65536];
    unsigned char* Amsg = SH;
    unsigned char* Ah0  = SH + 16384;
    float* LDSf = (float*)SH;

    const int tid  = threadIdx.x;
    const int lane = tid & 63;
    const int w    = tid >> 6;          // wave 0..7
    const int cbase = blockIdx.x * 64;  // first clause row of this block

    // ---- Phase A: rowptr slice -> lane regs; h0 tile cvt+stage (coalesced) ----
    int rp_l = 0;
    if (lane < 9) rp_l = rowptr_g[cbase + w * 8 + lane];

    #pragma unroll
    for (int q0 = 0; q0 < 2; ++q0) {
        int q = tid + q0 * 512;           // 1024 chunks: 64 rows x 16 x (8 values)
        int row = q >> 4;
        int j   = q & 15;
        frag_ab v;
        if constexpr (FP32IN) {
            v = load8_fp32((const float*)h0_ + (size_t)(cbase + row) * 128 + j * 8);
        } else {
            v = *reinterpret_cast<const frag_ab*>(
                (const unsigned short*)h0_ + (size_t)(cbase + row) * 128 + j * 8);
        }
        int byte = (j * 16) ^ ((row & 7) << 4);
        *reinterpret_cast<frag_ab*>(Ah0 + row * 256 + byte) = v;
    }

    // ---- Phase B: segment-sum, one quarter-wave per 2 clauses.
    //      Pair's edges are contiguous [st0,en1); 16 lit-indices preloaded in ONE
    //      parallel round (lanes of the quarter), then 1-deep pipelined x_l gather.
    //      Lane l16 accumulates dims l16*8..+8; no cross-lane reduce. ----
    {
        const int qq  = lane >> 4;        // quarter 0..3
        const int l16 = lane & 15;
        const int qb  = qq * 16;          // preload window base lane
        int st0 = __shfl(rp_l, qq * 2);
        int mid = __shfl(rp_l, qq * 2 + 1);
        int en1 = __shfl(rp_l, qq * 2 + 2);
        int pidx = st0 + l16;
        int elit_r = edge_lit[pidx < n_edges ? pidx : 0];   // parallel preload (<=16 edges)

        #pragma unroll
        for (int cc2 = 0; cc2 < 2; ++cc2) {
            int stg = cc2 ? mid : st0;
            int eng = cc2 ? en1 : mid;
            int dd  = eng - stg;
            int off = stg - st0;
            float a[8] = {0.f, 0.f, 0.f, 0.f, 0.f, 0.f, 0.f, 0.f};
            if constexpr (FP32IN) {
                float4 p0{}, p1{};
                if (dd > 0) {
                    int j = off;
                    int lit = (j < 16) ? __shfl(elit_r, qb + j) : edge_lit[st0 + j];
                    const float* xr = (const float*)x_l_ + (size_t)lit * 128 + l16 * 8;
                    p0 = *reinterpret_cast<const float4*>(xr);
                    p1 = *reinterpret_cast<const float4*>(xr + 4);
                }
                for (int i = 0; i < dd; ++i) {
                    float4 u0 = p0, u1 = p1;
                    if (i + 1 < dd) {                 // issue next edge before adds
                        int j = off + i + 1;
                        int lit = (j < 16) ? __shfl(elit_r, qb + j) : edge_lit[st0 + j];
                        const float* xr = (const float*)x_l_ + (size_t)lit * 128 + l16 * 8;
                        p0 = *reinterpret_cast<const float4*>(xr);
                        p1 = *reinterpret_cast<const float4*>(xr + 4);
                    }
                    a[0] += u0.x; a[1] += u0.y; a[2] += u0.z; a[3] += u0.w;
                    a[4] += u1.x; a[5] += u1.y; a[6] += u1.z; a[7] += u1.w;
                }
            } else {
                frag_ab p{};
                if (dd > 0) {
                    int j = off;
                    int lit = (j < 16) ? __shfl(elit_r, qb + j) : edge_lit[st0 + j];
                    p = *reinterpret_cast<const frag_ab*>(
                        (const unsigned short*)x_l_ + (size_t)lit * 128 + l16 * 8);
                }
                for (int i = 0; i < dd; ++i) {
                    frag_ab u = p;
                    if (i + 1 < dd) {
                        int j = off + i + 1;
                        int lit = (j < 16) ? __shfl(elit_r, qb + j) : edge_lit[st0 + j];
                        p = *reinterpret_cast<const frag_ab*>(
                            (const unsigned short*)x_l_ + (size_t)lit * 128 + l16 * 8);
                    }
                    #pragma unroll
                    for (int j = 0; j < 8; ++j) a[j] += bf2f((unsigned short)u[j]);
                }
            }
            int cc = w * 8 + qq * 2 + cc2;            // msg row in block
            frag_ab o;
            #pragma unroll
            for (int j = 0; j < 8; ++j) o[j] = (short)f2bf(a[j]);
            int byte = (l16 * 16) ^ ((cc & 7) << 4);
            *reinterpret_cast<frag_ab*>(Amsg + cc * 256 + byte) = o;
        }
    }
    __syncthreads();   // single barrier: h0 tile + msg tile both ready

    // ---- Phase C: c0 prefetch (T14: issue early, consume after GEMM), then GEMM ----
    const int l15 = lane & 15;
    const int lq  = lane >> 4;  // 0..3 (k-chunk group)
    const int d = w * 16 + l15;

    float cold[4][4];
    #pragma unroll
    for (int mf = 0; mf < 4; ++mf) {
        #pragma unroll
        for (int r = 0; r < 4; ++r) {
            int m = cbase + mf * 16 + lq * 4 + r;
            if constexpr (FP32IN) cold[mf][r] = ((const float*)c0_)[(size_t)m * 128 + d];
            else cold[mf][r] = bf2f(((const unsigned short*)c0_)[(size_t)m * 128 + d]);
        }
    }

    frag_cd acc[4][4];
    #pragma unroll
    for (int g = 0; g < 4; ++g)
        #pragma unroll
        for (int mf = 0; mf < 4; ++mf)
            acc[g][mf] = (frag_cd){0.f, 0.f, 0.f, 0.f};

    const frag_ab* Bp = reinterpret_cast<const frag_ab*>(Bpack);
    float bi[4];
    #pragma unroll
    for (int g = 0; g < 4; ++g) bi[g] = bias[g * 128 + d];

    #pragma unroll
    for (int kk = 0; kk < 8; ++kk) {             // K = 256, 32 per step
        const unsigned char* At = (kk < 4) ? Amsg : Ah0;
        frag_ab afr[4];
        #pragma unroll
        for (int mf = 0; mf < 4; ++mf) {
            int row = mf * 16 + l15;
            int byte = ((kk & 3) * 64 + lq * 16) ^ ((row & 7) << 4);
            afr[mf] = *reinterpret_cast<const frag_ab*>(At + row * 256 + byte);
        }
        frag_ab bfr[4];
        #pragma unroll
        for (int g = 0; g < 4; ++g) {
            int n = g * 128 + w * 16 + l15;
            bfr[g] = Bp[(kk * 512 + n) * 4 + lq];
        }
        #pragma unroll
        for (int g = 0; g < 4; ++g)
            #pragma unroll
            for (int mf = 0; mf < 4; ++mf)
                acc[g][mf] = __builtin_amdgcn_mfma_f32_16x16x32_bf16(
                    afr[mf], bfr[g], acc[g][mf], 0, 0, 0);
    }

    // ---- Phase D: LSTM gate math (wave-local; c0 already in regs) ----
    #pragma unroll
    for (int mf = 0; mf < 4; ++mf) {
        #pragma unroll
        for (int r = 0; r < 4; ++r) {
            float gi = acc[0][mf][r] + bi[0];
            float gf = acc[1][mf][r] + bi[1];
            float gg = acc[2][mf][r] + bi[2];
            float go = acc[3][mf][r] + bi[3];
            float iv = sigm(gi);
            float fv = sigm(gf);
            float gv = tanh_fast(gg);
            float ov = sigm(go);
            float cn = fv * cold[mf][r] + iv * gv;
            float hn = ov * tanh_fast(cn);
            acc[0][mf][r] = hn;
            acc[1][mf][r] = cn;
        }
    }

    // ---- Phase E: stage h AND c through 64K LDS (chunk-XOR swizzle), one pass,
    //      then flush full-line coalesced. Swizzle: float4-chunk c' = c ^ (row&7). ----
    __syncthreads();                         // GEMM LDS reads done
    #pragma unroll
    for (int mf = 0; mf < 4; ++mf) {
        #pragma unroll
        for (int r = 0; r < 4; ++r) {
            int rl = mf * 16 + lq * 4 + r;
            int sw = ((((d >> 2) ^ (rl & 7)) << 2) | (d & 3));
            LDSf[rl * 128 + sw]        = acc[0][mf][r];   // h rows 0..63
            LDSf[8192 + rl * 128 + sw] = acc[1][mf][r];   // c rows 64..127
        }
    }
    __syncthreads();
    if constexpr (FP32IN) {
        float* outp = (float*)out_;
        #pragma unroll
        for (int q0 = 0; q0 < 8; ++q0) {
            int q = tid + q0 * 512;          // 4096 float4 chunks (h then c)
            int row = q >> 5;                // 0..127
            int j   = q & 31;
            float4 v = *reinterpret_cast<const float4*>(
                &LDSf[row * 128 + ((j ^ (row & 7)) << 2)]);
            int half = row >> 6, rl = row & 63;
            *reinterpret_cast<float4*>(
                outp + (size_t)half * n_clause * 128 + (size_t)(cbase + rl) * 128 + j * 4) = v;
        }
    } else {
        unsigned short* outp = (unsigned short*)out_;
        #pragma unroll
        for (int q0 = 0; q0 < 4; ++q0) {
            int q = tid + q0 * 512;          // 2048 chunks of 8 values
            int row = q >> 4;                // 0..127
            int jj  = q & 15;
            int j0 = 2 * jj, j1 = 2 * jj + 1;
            float4 f0 = *reinterpret_cast<const float4*>(
                &LDSf[row * 128 + ((j0 ^ (row & 7)) << 2)]);
            float4 f1 = *reinterpret_cast<const float4*>(
                &LDSf[row * 128 + ((j1 ^ (row & 7)) << 2)]);
            frag_ab o;
            o[0] = (short)f2bf(f0.x); o[1] = (short)f2bf(f0.y);
            o[2] = (short)f2bf(f0.z); o[3] = (short)f2bf(f0.w);
            o[4] = (short)f2bf(f1.x); o[5] = (short)f2bf(f1.y);
            o[6] = (short)f2bf(f1.z); o[7] = (short)f2bf(f1.w);
            int half = row >> 6, rl = row & 63;
            *reinterpret_cast<frag_ab*>(
                outp + (size_t)half * n_clause * 128 + (size_t)(cbase + rl) * 128 + jj * 8) = o;
        }
    }
}

extern "C" void kernel_launch(void* const* d_in, const int* in_sizes, int n_in,
                              void* d_out, int out_size, void* d_ws, size_t ws_size,
                              hipStream_t stream) {
    const void* x_l  = d_in[0];
    const void* h0   = d_in[1];
    const void* c0   = d_in[2];
    const void* W_ih = d_in[3];
    const void* W_hh = d_in[4];
    const void* b_ih = d_in[5];
    const void* b_hh = d_in[6];
    const int* edge_lit    = (const int*)d_in[7];
    const int* edge_clause = (const int*)d_in[8];

    int n_edges  = in_sizes[7];
    int n_clause = in_sizes[1] / 128;       // 400000
    int nblocks  = (n_clause + 63) / 64;    // 6250 exact

    unsigned char* ws = (unsigned char*)d_ws;
    unsigned short* Bpack = (unsigned short*)(ws + WS_BPACK_OFF);
    float* bias  = (float*)(ws + WS_BIAS_OFF);
    int* flag    = (int*)(ws + WS_FLAG_OFF);
    int* rowptr  = (int*)(ws + WS_ROWPTR_OFF);

    detect_fmt<<<1, 64, 0, stream>>>((const unsigned short*)x_l, flag);

    build_rowptr<<<(n_clause + 256) / 256, 256, 0, stream>>>(
        edge_clause, rowptr, n_edges, n_clause);

    prepack<1><<<64, 256, 0, stream>>>(W_ih, W_hh, b_ih, b_hh, Bpack, bias, flag);
    prepack<0><<<64, 256, 0, stream>>>(W_ih, W_hh, b_ih, b_hh, Bpack, bias, flag);

    lit2clause_fused<1><<<nblocks, 512, 0, stream>>>(
        x_l, h0, c0, Bpack, bias, rowptr, edge_lit, d_out, flag, n_edges, n_clause);
    lit2clause_fused<0><<<nblocks, 512, 0, stream>>>(
        x_l, h0, c0, Bpack, bias, rowptr, edge_lit, d_out, flag, n_edges, n_clause);
}

// Round 8
// 346.229 us; speedup vs baseline: 1.4541x; 1.4541x over previous
//
#include <hip/hip_runtime.h>
#include <hip/hip_bf16.h>

// Fused: segment_sum(x_l[edge_lit] by sorted edge_clause) -> [msg|h0] @ [W_ih|W_hh]^T + b
//        -> LSTM cell epilogue -> h_new, c_new.
// Structure = round-5 (best measured: 403us) + proven deltas:
//   - native bf16 cvt (R6), c0 reg-prefetch (R6)
//   - NEW: sigmoid/tanh via __builtin_amdgcn_rcpf/exp2f (kills ~700 VALU insts/thread
//     of IEEE division sequences; ~1ulp, inf-safe, way inside 0.111 threshold)
// Device float dtype (fp32 vs bf16) detected at runtime (flag in d_ws); both template
// variants launch, wrong one exits immediately.
// build_rowptr: CSR offsets for all clauses -> d_ws.
// prepack: W -> bf16 Bpack[kk][n][lq]*16B + fp32 bias sum in d_ws.
// Main: one block = 64 clause rows, 512 threads = 8 waves. LDS ~34.8 KB.
//   Phase A: rowptr slice -> lane regs (shfl); edge_lit slice -> LDS; h0 tile cvt+stage.
//   Phase B: segment-sum, quarter-wave per edge (4 edges in flight/wave), xor-reduce.
//   Phase C: c0 prefetch to regs, GEMM (A from LDS, B from prepacked global).
//   Phase D: LSTM gate math (rcp/exp2).
//   Phase E: h/c two-pass staged through 32K LDS -> full-line coalesced stores.
// Wave w owns output dims d in [w*16, w*16+16) for ALL 4 gates (epilogue wave-local).
// Reg budget: ~64 arch VGPR + 64 acc = 128 total -> 4 waves/SIMD bin (structural cap).

using frag_ab = __attribute__((ext_vector_type(8))) short;  // 8 bf16 (4 VGPRs)
using frag_cd = __attribute__((ext_vector_type(4))) float;  // 4 fp32

__device__ __forceinline__ float bf2f(unsigned short u) {
    union { unsigned u; float f; } v; v.u = ((unsigned)u) << 16; return v.f;
}
__device__ __forceinline__ unsigned short f2bf(float f) {
    __hip_bfloat16 h = __float2bfloat16(f);   // RNE, native cvt on gfx950
    return *reinterpret_cast<unsigned short*>(&h);
}
// sigmoid = rcp(1 + 2^(-x*log2e)); 1 v_exp + 1 v_add + 1 v_rcp, no div sequence.
__device__ __forceinline__ float sigm(float x) {
    return __builtin_amdgcn_rcpf(1.0f + __builtin_amdgcn_exp2f(-1.442695040889f * x));
}
// tanh(x) = 2*sigmoid(2x) - 1; inf-safe (rcp(inf)=0 -> +/-1).
__device__ __forceinline__ float tanh_fast(float x) {
    float s = __builtin_amdgcn_rcpf(1.0f + __builtin_amdgcn_exp2f(-2.885390081777f * x));
    return __builtin_fmaf(2.0f, s, -1.0f);
}
__device__ __forceinline__ frag_ab load8_fp32(const float* p) {
    float4 a = *reinterpret_cast<const float4*>(p);
    float4 b = *reinterpret_cast<const float4*>(p + 4);
    frag_ab r;
    r[0] = (short)f2bf(a.x); r[1] = (short)f2bf(a.y);
    r[2] = (short)f2bf(a.z); r[3] = (short)f2bf(a.w);
    r[4] = (short)f2bf(b.x); r[5] = (short)f2bf(b.y);
    r[6] = (short)f2bf(b.z); r[7] = (short)f2bf(b.w);
    return r;
}

// ws layout
#define WS_BPACK_OFF  0           // 16384 * 16B = 256 KB
#define WS_BIAS_OFF   262144     // 512 * 4B
#define WS_FLAG_OFF   264192     // 4B
#define WS_ROWPTR_OFF 264704     // (n_clause+1) * 4B  (~1.6 MB)

#define EDGE_CAP 512             // LDS-staged edges per block (global fallback beyond)

// Decide device float dtype: sample even-indexed 16-bit words of x_l.
// fp32 -> low mantissa halves (uniform) -> ~25% have exp field >= 0xC0.
// bf16 -> values of N(0,1) -> exp field < 0x90 always.
__global__ void detect_fmt(const unsigned short* __restrict__ x, int* __restrict__ flag) {
    int t = threadIdx.x;
    int cnt = 0;
    for (int i = t; i < 4096; i += 64) {
        unsigned e = (x[2 * i] >> 7) & 0xFF;
        cnt += (e >= 0xC0) ? 1 : 0;
    }
    #pragma unroll
    for (int s = 32; s; s >>= 1) cnt += __shfl_xor(cnt, s);
    if (t == 0) *flag = (cnt > 64) ? 1 : 0;   // 1 = fp32, 0 = bf16
}

// CSR row offsets for every clause (dtype-independent).
__global__ void build_rowptr(const int* __restrict__ edge_clause, int* __restrict__ rowptr,
                             int n_edges, int n_clause) {
    int idx = blockIdx.x * blockDim.x + threadIdx.x;
    if (idx > n_clause) return;
    int lo = 0, hi = n_edges;
    while (lo < hi) {
        int mid = (lo + hi) >> 1;
        if (edge_clause[mid] < idx) lo = mid + 1; else hi = mid;
    }
    rowptr[idx] = lo;
}

// Pack W_ih/W_hh into bf16 Bpack: chunk idx = (kk*512 + n)*4 + lq holds 8 bf16 of
// k = (kk&3)*32 + lq*8 .. +8 from row n of (kk<4 ? W_ih : W_hh). Also bias sum fp32.
template <int FP32IN>
__global__ void prepack(const void* __restrict__ W_ih_, const void* __restrict__ W_hh_,
                        const void* __restrict__ b_ih_, const void* __restrict__ b_hh_,
                        unsigned short* __restrict__ Bpack, float* __restrict__ bias,
                        const int* __restrict__ flag) {
    if (*flag != FP32IN) return;
    int idx = blockIdx.x * blockDim.x + threadIdx.x;
    if (idx < 16384) {
        int kk = idx >> 11;
        int n  = (idx >> 2) & 511;
        int lq = idx & 3;
        int ksrc = (kk & 3) * 32 + lq * 8;
        frag_ab v;
        if constexpr (FP32IN) {
            const float* W = (kk < 4) ? (const float*)W_ih_ : (const float*)W_hh_;
            v = load8_fp32(W + (size_t)n * 128 + ksrc);
        } else {
            const unsigned short* W =
                (kk < 4) ? (const unsigned short*)W_ih_ : (const unsigned short*)W_hh_;
            v = *reinterpret_cast<const frag_ab*>(W + (size_t)n * 128 + ksrc);
        }
        *reinterpret_cast<frag_ab*>(Bpack + (size_t)idx * 8) = v;
    }
    if (idx < 512) {
        float b;
        if constexpr (FP32IN)
            b = ((const float*)b_ih_)[idx] + ((const float*)b_hh_)[idx];
        else
            b = bf2f(((const unsigned short*)b_ih_)[idx]) +
                bf2f(((const unsigned short*)b_hh_)[idx]);
        bias[idx] = b;
    }
}

template <int FP32IN>
__global__ __launch_bounds__(512, 4) void lit2clause_fused(
    const void* __restrict__ x_l_,
    const void* __restrict__ h0_,
    const void* __restrict__ c0_,
    const unsigned short* __restrict__ Bpack,
    const float* __restrict__ bias,
    const int*  __restrict__ rowptr_g,
    const int*  __restrict__ edge_lit,
    void* __restrict__ out_,
    const int* __restrict__ fmt_flag,
    int n_clause)
{
    if (*fmt_flag != FP32IN) return;   // wrong-dtype variant: bail (uniform, pre-barrier)

    // SH: [msg 16K | h0 16K] bf16 [64][128], 256B/row, XOR swizzle byte^=(row&7)<<4.
    // Reused post-GEMM as fp32 [64][128] out-staging (two passes: h then c).
    __shared__ __align__(16) unsigned char SH[32768];
    __shared__ int elits[EDGE_CAP];
    unsigned char* Amsg = SH;
    unsigned char* Ah0  = SH + 16384;
    float* LDSf = (float*)SH;

    const int tid  = threadIdx.x;
    const int lane = tid & 63;
    const int w    = tid >> 6;          // wave 0..7
    const int cbase = blockIdx.x * 64;  // first clause row of this block

    // ---- Phase A: rowptr -> lane regs; edge_lit slice -> LDS; h0 tile cvt+stage ----
    int rp_l = 0;
    if (lane < 9) rp_l = rowptr_g[cbase + w * 8 + lane];

    const int eBase = rowptr_g[cbase];
    const int eEnd  = rowptr_g[cbase + 64];
    const int eCount = eEnd - eBase;
    for (int i = tid; i < eCount && i < EDGE_CAP; i += 512)
        elits[i] = edge_lit[eBase + i];

    #pragma unroll
    for (int q0 = 0; q0 < 2; ++q0) {
        int q = tid + q0 * 512;           // 1024 chunks: 64 rows x 16 x (8 values)
        int row = q >> 4;
        int j   = q & 15;
        frag_ab v;
        if constexpr (FP32IN) {
            v = load8_fp32((const float*)h0_ + (size_t)(cbase + row) * 128 + j * 8);
        } else {
            v = *reinterpret_cast<const frag_ab*>(
                (const unsigned short*)h0_ + (size_t)(cbase + row) * 128 + j * 8);
        }
        int byte = (j * 16) ^ ((row & 7) << 4);
        *reinterpret_cast<frag_ab*>(Ah0 + row * 256 + byte) = v;
    }
    __syncthreads();

    // ---- Phase B: segment-sum x_l into msg tile. Quarter-wave per edge:
    //      4 edges in flight/wave, 32B/lane; reduce via shfl_xor(16/32). ----
    {
        const int q   = lane >> 4;    // quarter 0..3 -> edge e = st + q + 4*i
        const int l16 = lane & 15;    // 8 floats per lane
        for (int s = 0; s < 8; ++s) {
            int cc = w * 8 + s;
            int st = __shfl(rp_l, s)     - eBase;
            int en = __shfl(rp_l, s + 1) - eBase;
            float a[8] = {0.f, 0.f, 0.f, 0.f, 0.f, 0.f, 0.f, 0.f};
            for (int e = st + q; e < en; e += 4) {
                int lit = (e < EDGE_CAP) ? elits[e] : edge_lit[eBase + e];
                if constexpr (FP32IN) {
                    const float* xr = (const float*)x_l_ + (size_t)lit * 128 + l16 * 8;
                    float4 v0 = *reinterpret_cast<const float4*>(xr);
                    float4 v1 = *reinterpret_cast<const float4*>(xr + 4);
                    a[0] += v0.x; a[1] += v0.y; a[2] += v0.z; a[3] += v0.w;
                    a[4] += v1.x; a[5] += v1.y; a[6] += v1.z; a[7] += v1.w;
                } else {
                    const unsigned short* xr =
                        (const unsigned short*)x_l_ + (size_t)lit * 128 + l16 * 8;
                    frag_ab v = *reinterpret_cast<const frag_ab*>(xr);
                    #pragma unroll
                    for (int j = 0; j < 8; ++j) a[j] += bf2f((unsigned short)v[j]);
                }
            }
            #pragma unroll
            for (int j = 0; j < 8; ++j) {
                a[j] += __shfl_xor(a[j], 16);
                a[j] += __shfl_xor(a[j], 32);
            }
            if (q == 0) {
                frag_ab o;
                #pragma unroll
                for (int j = 0; j < 8; ++j) o[j] = (short)f2bf(a[j]);
                int byte = (l16 * 16) ^ ((cc & 7) << 4);
                *reinterpret_cast<frag_ab*>(Amsg + cc * 256 + byte) = o;
            }
        }
    }
    __syncthreads();   // msg + h0 tiles ready

    // ---- Phase C: c0 prefetch (issue early, consume after GEMM), then GEMM ----
    const int l15 = lane & 15;
    const int lq  = lane >> 4;  // 0..3 (k-chunk group)
    const int d = w * 16 + l15;

    float cold[4][4];
    #pragma unroll
    for (int mf = 0; mf < 4; ++mf) {
        #pragma unroll
        for (int r = 0; r < 4; ++r) {
            int m = cbase + mf * 16 + lq * 4 + r;
            if constexpr (FP32IN) cold[mf][r] = ((const float*)c0_)[(size_t)m * 128 + d];
            else cold[mf][r] = bf2f(((const unsigned short*)c0_)[(size_t)m * 128 + d]);
        }
    }

    frag_cd acc[4][4];
    #pragma unroll
    for (int g = 0; g < 4; ++g)
        #pragma unroll
        for (int mf = 0; mf < 4; ++mf)
            acc[g][mf] = (frag_cd){0.f, 0.f, 0.f, 0.f};

    const frag_ab* Bp = reinterpret_cast<const frag_ab*>(Bpack);
    float bi[4];
    #pragma unroll
    for (int g = 0; g < 4; ++g) bi[g] = bias[g * 128 + d];

    #pragma unroll
    for (int kk = 0; kk < 8; ++kk) {             // K = 256, 32 per step
        const unsigned char* At = (kk < 4) ? Amsg : Ah0;
        frag_ab afr[4];
        #pragma unroll
        for (int mf = 0; mf < 4; ++mf) {
            int row = mf * 16 + l15;
            int byte = ((kk & 3) * 64 + lq * 16) ^ ((row & 7) << 4);
            afr[mf] = *reinterpret_cast<const frag_ab*>(At + row * 256 + byte);
        }
        frag_ab bfr[4];
        #pragma unroll
        for (int g = 0; g < 4; ++g) {
            int n = g * 128 + w * 16 + l15;
            bfr[g] = Bp[(kk * 512 + n) * 4 + lq];
        }
        #pragma unroll
        for (int g = 0; g < 4; ++g)
            #pragma unroll
            for (int mf = 0; mf < 4; ++mf)
                acc[g][mf] = __builtin_amdgcn_mfma_f32_16x16x32_bf16(
                    afr[mf], bfr[g], acc[g][mf], 0, 0, 0);
    }

    // ---- Phase D: LSTM gate math (wave-local; c0 already in regs; rcp/exp2) ----
    #pragma unroll
    for (int mf = 0; mf < 4; ++mf) {
        #pragma unroll
        for (int r = 0; r < 4; ++r) {
            float gi = acc[0][mf][r] + bi[0];
            float gf = acc[1][mf][r] + bi[1];
            float gg = acc[2][mf][r] + bi[2];
            float go = acc[3][mf][r] + bi[3];
            float iv = sigm(gi);
            float fv = sigm(gf);
            float gv = tanh_fast(gg);
            float ov = sigm(go);
            float cn = fv * cold[mf][r] + iv * gv;
            float hn = ov * tanh_fast(cn);
            acc[0][mf][r] = hn;
            acc[1][mf][r] = cn;
        }
    }

    // ---- Phase E: stage h/c through 32K LDS (chunk-XOR swizzle), two passes,
    //      flush full-line coalesced. Swizzle: float4-chunk c' = c ^ (row&7). ----
    #pragma unroll
    for (int half = 0; half < 2; ++half) {       // 0 = h_new, 1 = c_new
        __syncthreads();                         // prior LDS use done
        #pragma unroll
        for (int mf = 0; mf < 4; ++mf) {
            #pragma unroll
            for (int r = 0; r < 4; ++r) {
                int rl = mf * 16 + lq * 4 + r;
                int idx = rl * 128 + ((((d >> 2) ^ (rl & 7)) << 2) | (d & 3));
                LDSf[idx] = acc[half][mf][r];
            }
        }
        __syncthreads();
        if constexpr (FP32IN) {
            float* outp = (float*)out_ + (size_t)half * n_clause * 128;
            #pragma unroll
            for (int q0 = 0; q0 < 4; ++q0) {
                int q = tid + q0 * 512;          // 2048 float4 chunks
                int row = q >> 5;
                int j   = q & 31;
                float4 v = *reinterpret_cast<const float4*>(
                    &LDSf[row * 128 + ((j ^ (row & 7)) << 2)]);
                *reinterpret_cast<float4*>(outp + (size_t)(cbase + row) * 128 + j * 4) = v;
            }
        } else {
            unsigned short* outp = (unsigned short*)out_ + (size_t)half * n_clause * 128;
            #pragma unroll
            for (int q0 = 0; q0 < 2; ++q0) {
                int q = tid + q0 * 512;          // 1024 chunks of 8 values
                int row = q >> 4;
                int jj  = q & 15;
                int j0 = 2 * jj, j1 = 2 * jj + 1;
                float4 f0 = *reinterpret_cast<const float4*>(
                    &LDSf[row * 128 + ((j0 ^ (row & 7)) << 2)]);
                float4 f1 = *reinterpret_cast<const float4*>(
                    &LDSf[row * 128 + ((j1 ^ (row & 7)) << 2)]);
                frag_ab o;
                o[0] = (short)f2bf(f0.x); o[1] = (short)f2bf(f0.y);
                o[2] = (short)f2bf(f0.z); o[3] = (short)f2bf(f0.w);
                o[4] = (short)f2bf(f1.x); o[5] = (short)f2bf(f1.y);
                o[6] = (short)f2bf(f1.z); o[7] = (short)f2bf(f1.w);
                *reinterpret_cast<frag_ab*>(outp + (size_t)(cbase + row) * 128 + jj * 8) = o;
            }
        }
    }
}

extern "C" void kernel_launch(void* const* d_in, const int* in_sizes, int n_in,
                              void* d_out, int out_size, void* d_ws, size_t ws_size,
                              hipStream_t stream) {
    const void* x_l  = d_in[0];
    const void* h0   = d_in[1];
    const void* c0   = d_in[2];
    const void* W_ih = d_in[3];
    const void* W_hh = d_in[4];
    const void* b_ih = d_in[5];
    const void* b_hh = d_in[6];
    const int* edge_lit    = (const int*)d_in[7];
    const int* edge_clause = (const int*)d_in[8];

    int n_edges  = in_sizes[7];
    int n_clause = in_sizes[1] / 128;       // 400000
    int nblocks  = (n_clause + 63) / 64;    // 6250 exact

    unsigned char* ws = (unsigned char*)d_ws;
    unsigned short* Bpack = (unsigned short*)(ws + WS_BPACK_OFF);
    float* bias  = (float*)(ws + WS_BIAS_OFF);
    int* flag    = (int*)(ws + WS_FLAG_OFF);
    int* rowptr  = (int*)(ws + WS_ROWPTR_OFF);

    detect_fmt<<<1, 64, 0, stream>>>((const unsigned short*)x_l, flag);

    build_rowptr<<<(n_clause + 256) / 256, 256, 0, stream>>>(
        edge_clause, rowptr, n_edges, n_clause);

    prepack<1><<<64, 256, 0, stream>>>(W_ih, W_hh, b_ih, b_hh, Bpack, bias, flag);
    prepack<0><<<64, 256, 0, stream>>>(W_ih, W_hh, b_ih, b_hh, Bpack, bias, flag);

    lit2clause_fused<1><<<nblocks, 512, 0, stream>>>(
        x_l, h0, c0, Bpack, bias, rowptr, edge_lit, d_out, flag, n_clause);
    lit2clause_fused<0><<<nblocks, 512, 0, stream>>>(
        x_l, h0, c0, Bpack, bias, rowptr, edge_lit, d_out, flag, n_clause);
}